// Round 4
// baseline (298.765 us; speedup 1.0000x reference)
//
#include <hip/hip_runtime.h>
#include <math.h>

typedef __attribute__((ext_vector_type(8))) short short8;
typedef __attribute__((ext_vector_type(16))) float f32x16;

#define XS_STRIDE 72   // shorts per (row,col) cell: 64 ci + 8 pad -> 144 B, 16B-aligned
#define NBLOCKS (16 * 64 * 2)

__device__ __forceinline__ short f2bf(float f) {
    union { float f; unsigned u; } v; v.f = f;
    unsigned r = (v.u + 0x7FFFu + ((v.u >> 16) & 1u)) >> 16;
    return (short)r;
}

// prep: blocks 0..127 build weight A-fragments (MFMA 32x32x16 layout, per parity);
// blocks 128..143 zero the 4096-float accumulator; block 128 zeroes the counter.
// wfrag[p][q][lane][j]: p=ph*2+pw, q=tap*4+ci_block, lane&31=co,
// ci=(q&3)*16+(lane>>5)*8+j, tap t=(a,b): kh=2a+1-ph, kw=2b+1-pw.
__global__ void prep(const float* __restrict__ w, short* __restrict__ wfrag,
                     float* __restrict__ acc, unsigned* __restrict__ counter) {
    int b = blockIdx.x, t = threadIdx.x;
    if (b < 128) {
        int idx = b * 256 + t;                  // 0 .. 32767
        int j    = idx & 7;
        int lane = (idx >> 3) & 63;
        int q    = (idx >> 9) & 15;
        int p    = idx >> 13;
        int co = lane & 31, half = lane >> 5;
        int ci = (q & 3) * 16 + half * 8 + j;
        int tp = q >> 2, a = tp >> 1, bb = tp & 1;
        int ph = p >> 1, pw = p & 1;
        int kh = 2 * a + 1 - ph, kw = 2 * bb + 1 - pw;
        wfrag[idx] = f2bf(w[((ci * 32 + co) * 4 + kh) * 4 + kw]);
    } else {
        acc[(b - 128) * 256 + t] = 0.f;
        if (b == 128 && t == 0) *counter = 0u;
    }
}

// Block = (n, input row pair i0..i0+1, col half jh). Stages x rows i0-1..i0+2
// as bf16 to LDS, 4 waves = 4 output parities, each runs GEMM co(32) x
// pixels(32) x K(256) per row-pair with mfma_f32_32x32x16_bf16, min over co,
// parity+row-pair sum -> one atomicAdd per (n,ow). Last block (atomic counter)
// applies GELU+bias to the 4096 accumulated sums and writes out.
__global__ __launch_bounds__(256, 4) void convt_mfma(
    const float* __restrict__ x, const short* __restrict__ wfrag,
    const float* __restrict__ conv_b, const float* __restrict__ bias,
    float* __restrict__ acc4096, unsigned* __restrict__ counter,
    float* __restrict__ out)
{
    __shared__ short xs[4][66][XS_STRIDE];   // [row][col(-1..64)][ci], 38 KB
    __shared__ float minbuf[2][4][64];       // [rp][parity][col]
    __shared__ unsigned lastflag;

    int blk = blockIdx.x;
    int jh = blk & 1;
    int i0 = ((blk >> 1) & 63) * 2;
    int n  = blk >> 7;
    int t  = threadIdx.x;

    // ---- stage x rows i0-1..i0+2, global cols jh*64-1 .. jh*64+64 (zero pad) ----
    {
        int col  = t & 63;
        int cih  = (t >> 6) * 4;            // 4 consecutive ci per thread
        int gcol = jh * 64 + col;
        for (int r = 0; r < 4; ++r) {
            int gi = i0 - 1 + r;
            bool rowok = (unsigned)gi < 128u;
            int gic = rowok ? gi : 0;
            for (int g = 0; g < 4; ++g) {
                int ci = g * 16 + cih;
                const float* px = x + (((size_t)(n * 64 + ci) * 128 + gic) * 128 + gcol);
                float v0 = rowok ? px[0]     : 0.f;
                float v1 = rowok ? px[16384] : 0.f;   // +1 ci plane
                float v2 = rowok ? px[32768] : 0.f;
                float v3 = rowok ? px[49152] : 0.f;
                union { short s[4]; unsigned long long u; } pk;
                pk.s[0] = f2bf(v0); pk.s[1] = f2bf(v1);
                pk.s[2] = f2bf(v2); pk.s[3] = f2bf(v3);
                *(unsigned long long*)&xs[r][col + 1][ci] = pk.u;
            }
        }
        {   // halo cols: local 0 (g=-1) and 65 (g=+64), 4 rows x 64 ci
            int r = t >> 6, ci = t & 63, gi = i0 - 1 + r;
            for (int side = 0; side < 2; ++side) {
                int gc = jh * 64 + (side ? 64 : -1);
                float v = ((unsigned)gi < 128u && (unsigned)gc < 128u)
                        ? x[((size_t)(n * 64 + ci) * 128 + gi) * 128 + gc] : 0.f;
                xs[r][side ? 65 : 0][ci] = f2bf(v);
            }
        }
    }
    __syncthreads();

    int wv = t >> 6, lane = t & 63;        // wave = parity (ph,pw)
    int ph = wv >> 1, pw = wv & 1;
    int ln = lane & 31, half = lane >> 5;

    // A fragments: 16 chunks x 8 bf16/lane, resident in VGPRs
    short8 af[16];
    const short8* wf = (const short8*)(wfrag + wv * 8192);
    #pragma unroll
    for (int q = 0; q < 16; ++q) af[q] = wf[q * 64 + lane];

    // conv_b seed in C/D layout: row(co) = (reg&3) + 8*(reg>>2) + 4*half (m74/m101)
    float cb[16];
    #pragma unroll
    for (int reg = 0; reg < 16; ++reg) {
        int co = (reg & 3) + 8 * (reg >> 2) + 4 * half;
        cb[reg] = conv_b[co];
    }

    #pragma unroll
    for (int rp = 0; rp < 2; ++rp) {
        for (int j0 = 0; j0 < 64; j0 += 32) {
            f32x16 acc;
            #pragma unroll
            for (int reg = 0; reg < 16; ++reg) acc[reg] = cb[reg];
            #pragma unroll
            for (int q = 0; q < 16; ++q) {
                int tq = q >> 2, a = tq >> 1, b = tq & 1;
                int ridx = rp + 1 + ph - a;               // row (i0+rp) + dh
                int colp = j0 + ln + (pw - b) + 1;        // col j + dw
                int ci0  = (q & 3) * 16 + half * 8;
                const short8* bp = (const short8*)&xs[ridx][colp][ci0];  // ds_read_b128
                acc = __builtin_amdgcn_mfma_f32_32x32x16_bf16(af[q], *bp, acc, 0, 0, 0);
            }
            float mn = acc[0];
            #pragma unroll
            for (int reg = 1; reg < 16; ++reg) mn = fminf(mn, acc[reg]);
            mn = fminf(mn, __shfl_xor(mn, 32, 64));       // fold co halves
            if (half == 0) minbuf[rp][wv][j0 + ln] = mn;
        }
    }
    __syncthreads();

    // fold rp (same acc address) + ph -> one atomicAdd per (n,ow), 128/block
    if (t < 128) {
        int pw2 = (t >> 6) & 1;
        int jl  = t & 63;
        float v = minbuf[0][pw2][jl] + minbuf[0][2 + pw2][jl]
                + minbuf[1][pw2][jl] + minbuf[1][2 + pw2][jl];
        int ow = ((jh * 64 + jl) << 1) | pw2;
        atomicAdd(&acc4096[n * 256 + ow], v);
    }
    __threadfence();
    __syncthreads();

    // last-block finalize: GELU(tanh) + bias on the 4096 sums
    if (t == 0) {
        unsigned old = __hip_atomic_fetch_add(counter, 1u, __ATOMIC_ACQ_REL,
                                              __HIP_MEMORY_SCOPE_AGENT);
        lastflag = (old == (unsigned)(NBLOCKS - 1)) ? 1u : 0u;
    }
    __syncthreads();
    if (lastflag) {
        float b0 = bias[0];
        for (int k = t; k < 4096; k += 256) {
            float s = __hip_atomic_load(&acc4096[k], __ATOMIC_RELAXED,
                                        __HIP_MEMORY_SCOPE_AGENT);
            float u = 0.7978845608028654f * (s + 0.044715f * s * s * s);
            out[k] = 0.5f * s * (1.f + tanhf(u)) + b0;
        }
    }
}

extern "C" void kernel_launch(void* const* d_in, const int* in_sizes, int n_in,
                              void* d_out, int out_size, void* d_ws, size_t ws_size,
                              hipStream_t stream) {
    const float* x      = (const float*)d_in[0];   // [16,64,128,128]
    const float* w      = (const float*)d_in[1];   // [64,32,4,4]
    const float* conv_b = (const float*)d_in[2];   // [32]
    const float* bias   = (const float*)d_in[3];   // [1]
    float* out = (float*)d_out;                    // 16*256

    float*    acc     = (float*)d_ws;                        // 4096 floats
    unsigned* counter = (unsigned*)((char*)d_ws + 16384);    // 1 uint
    short*    wfrag   = (short*)((char*)d_ws + 16448);       // 32768 shorts, 16B-aligned

    hipLaunchKernelGGL(prep, dim3(144), dim3(256), 0, stream, w, wfrag, acc, counter);
    hipLaunchKernelGGL(convt_mfma, dim3(NBLOCKS), dim3(256), 0, stream,
                       x, wfrag, conv_b, bias, acc, counter, out);
}

// Round 5
// 259.464 us; speedup vs baseline: 1.1515x; 1.1515x over previous
//
#include <hip/hip_runtime.h>
#include <hip/hip_cooperative_groups.h>
#include <math.h>

namespace cg = cooperative_groups;

typedef __attribute__((ext_vector_type(8))) short short8;
typedef __attribute__((ext_vector_type(16))) float f32x16;

#define XS_STRIDE 72   // shorts per (row,col) cell: 64 ci + 8 pad, 16B-aligned
#define NITEMS (16 * 64 * 2)

__device__ __forceinline__ short f2bf(float f) {
    union { float f; unsigned u; } v; v.f = f;
    unsigned r = (v.u + 0x7FFFu + ((v.u >> 16) & 1u)) >> 16;
    return (short)r;
}

// Single cooperative kernel:
//  phase 1: grid-stride over items (n, row-pair i0, col-half jh). Stage x rows
//           i0-1..i0+2 as bf16 to LDS; 4 waves = 4 output parities; GEMM
//           co(32) x pixels(32) x K(256) via mfma_f32_32x32x16_bf16; min over
//           co; fold parities/row-pair -> partial[n][ow][i0/2] (plain store,
//           each slot written once).
//  grid.sync()
//  phase 2: blocks 0..15 sum 64 contiguous partials per (n,ow), GELU+bias.
__global__ __launch_bounds__(256, 4) void convt_fused(
    const float* __restrict__ x, const float* __restrict__ w,
    const float* __restrict__ conv_b, const float* __restrict__ bias,
    float* __restrict__ partial, float* __restrict__ out)
{
    __shared__ short xs[4][66][XS_STRIDE];   // 38016 B
    __shared__ float minbuf[2][4][64];       // 2048 B

    int t = threadIdx.x;
    int wv = t >> 6, lane = t & 63;          // wave = parity (ph,pw)
    int ph = wv >> 1, pw = wv & 1;
    int ln = lane & 31, half = lane >> 5;

    // ---- per-wave A fragments straight from global w (L2-resident, once) ----
    // af[q][j]: ci=(q&3)*16+half*8+j, co=ln, tap t=(a,b): kh=2a+1-ph, kw=2b+1-pw
    short8 af[16];
    #pragma unroll
    for (int q = 0; q < 16; ++q) {
        int tq = q >> 2, a = tq >> 1, b = tq & 1;
        int kh = 2 * a + 1 - ph, kw = 2 * b + 1 - pw;
        int cib = (q & 3) * 16 + half * 8;
        #pragma unroll
        for (int j = 0; j < 8; ++j)
            af[q][j] = f2bf(w[(((cib + j) * 32 + ln) * 4 + kh) * 4 + kw]);
    }
    // conv_b seed in C/D layout: row(co) = (reg&3) + 8*(reg>>2) + 4*half (m74/m101)
    float cb[16];
    #pragma unroll
    for (int reg = 0; reg < 16; ++reg)
        cb[reg] = conv_b[(reg & 3) + 8 * (reg >> 2) + 4 * half];

    for (int item = blockIdx.x; item < NITEMS; item += gridDim.x) {
        int jh = item & 1;
        int i0 = ((item >> 1) & 63) * 2;
        int n  = item >> 7;

        // ---- stage x rows i0-1..i0+2, cols jh*64-1 .. jh*64+64 (zero pad) ----
        {
            int col  = t & 63;
            int cih  = (t >> 6) * 4;            // 4 consecutive ci per thread
            int gcol = jh * 64 + col;
            for (int r = 0; r < 4; ++r) {
                int gi = i0 - 1 + r;
                bool rowok = (unsigned)gi < 128u;
                int gic = rowok ? gi : 0;
                #pragma unroll
                for (int g = 0; g < 4; ++g) {
                    int ci = g * 16 + cih;
                    const float* px = x + (((size_t)(n * 64 + ci) * 128 + gic) * 128 + gcol);
                    float v0 = rowok ? px[0]     : 0.f;
                    float v1 = rowok ? px[16384] : 0.f;   // +1 ci plane
                    float v2 = rowok ? px[32768] : 0.f;
                    float v3 = rowok ? px[49152] : 0.f;
                    union { short s[4]; unsigned long long u; } pk;
                    pk.s[0] = f2bf(v0); pk.s[1] = f2bf(v1);
                    pk.s[2] = f2bf(v2); pk.s[3] = f2bf(v3);
                    *(unsigned long long*)&xs[r][col + 1][ci] = pk.u;
                }
            }
            {   // halo cols: local 0 (g=-1) and 65 (g=+64), 4 rows x 64 ci
                int r = t >> 6, ci = t & 63, gi = i0 - 1 + r;
                for (int side = 0; side < 2; ++side) {
                    int gc = jh * 64 + (side ? 64 : -1);
                    float v = ((unsigned)gi < 128u && (unsigned)gc < 128u)
                            ? x[((size_t)(n * 64 + ci) * 128 + gi) * 128 + gc] : 0.f;
                    xs[r][side ? 65 : 0][ci] = f2bf(v);
                }
            }
        }
        __syncthreads();

        #pragma unroll
        for (int rp = 0; rp < 2; ++rp) {
            for (int j0 = 0; j0 < 64; j0 += 32) {
                f32x16 acc;
                #pragma unroll
                for (int reg = 0; reg < 16; ++reg) acc[reg] = cb[reg];
                #pragma unroll
                for (int q = 0; q < 16; ++q) {
                    int tq = q >> 2, a = tq >> 1, b = tq & 1;
                    int ridx = rp + 1 + ph - a;               // row (i0+rp) + dh
                    int colp = j0 + ln + (pw - b) + 1;        // col j + dw
                    int ci0  = (q & 3) * 16 + half * 8;
                    const short8* bp = (const short8*)&xs[ridx][colp][ci0];
                    acc = __builtin_amdgcn_mfma_f32_32x32x16_bf16(af[q], *bp, acc, 0, 0, 0);
                }
                float mn = acc[0];
                #pragma unroll
                for (int reg = 1; reg < 16; ++reg) mn = fminf(mn, acc[reg]);
                mn = fminf(mn, __shfl_xor(mn, 32, 64));       // fold co halves
                if (half == 0) minbuf[rp][wv][j0 + ln] = mn;
            }
        }
        __syncthreads();

        // fold rp + ph -> one plain store per (n,ow): partial[n][ow][i0/2]
        if (t < 128) {
            int pw2 = (t >> 6) & 1;
            int jl  = t & 63;
            float v = minbuf[0][pw2][jl] + minbuf[0][2 + pw2][jl]
                    + minbuf[1][pw2][jl] + minbuf[1][2 + pw2][jl];
            int ow = ((jh * 64 + jl) << 1) | pw2;
            partial[((size_t)(n * 256) + ow) * 64 + (i0 >> 1)] = v;
        }
        // no barrier needed: xs reads all precede the barrier above; minbuf
        // is rewritten only after the next iteration's staging barrier.
    }

    cg::this_grid().sync();

    // ---- phase 2: finalize 4096 outputs on blocks 0..15 ----
    if (blockIdx.x < 16) {
        int k = blockIdx.x * 256 + t;
        const float4* p = (const float4*)(partial + (size_t)k * 64);
        float s = 0.f;
        #pragma unroll
        for (int q = 0; q < 16; ++q) {
            float4 v = p[q];
            s += v.x + v.y + v.z + v.w;
        }
        float u = 0.7978845608028654f * (s + 0.044715f * s * s * s);
        out[k] = 0.5f * s * (1.f + tanhf(u)) + bias[0];
    }
}

extern "C" void kernel_launch(void* const* d_in, const int* in_sizes, int n_in,
                              void* d_out, int out_size, void* d_ws, size_t ws_size,
                              hipStream_t stream) {
    const float* x      = (const float*)d_in[0];   // [16,64,128,128]
    const float* w      = (const float*)d_in[1];   // [64,32,4,4]
    const float* conv_b = (const float*)d_in[2];   // [32]
    const float* bias   = (const float*)d_in[3];   // [1]
    float* out     = (float*)d_out;                // 16*256
    float* partial = (float*)d_ws;                 // 16*256*64 fp32 = 1 MB

    int maxb = 4;
    hipOccupancyMaxActiveBlocksPerMultiprocessor(&maxb, (const void*)convt_fused, 256, 0);
    if (maxb < 1) maxb = 1;
    int nb = maxb * 256;                           // 256 CUs on MI355X
    if (nb > NITEMS) nb = NITEMS;

    void* args[] = {(void*)&x, (void*)&w, (void*)&conv_b, (void*)&bias,
                    (void*)&partial, (void*)&out};
    hipLaunchCooperativeKernel((void*)convt_fused, dim3(nb), dim3(256),
                               args, 0, stream);
}

// Round 6
// 176.453 us; speedup vs baseline: 1.6932x; 1.4704x over previous
//
#include <hip/hip_runtime.h>
#include <math.h>

typedef __attribute__((ext_vector_type(8))) short short8;
typedef __attribute__((ext_vector_type(16))) float f32x16;

#define NITEMS (16 * 64 * 2)

__device__ __forceinline__ short f2bf(float f) {
    union { float f; unsigned u; } v; v.f = f;
    unsigned r = (v.u + 0x7FFFu + ((v.u >> 16) & 1u)) >> 16;
    return (short)r;
}

// prep_transpose: block (n,h) transposes x[n][:,h,:] fp32 -> xT[n][h][w][ci]
// bf16 with NO LDS: lane l (=w) reads 8 consecutive ci rows coalesced and
// already holds pixel l's 8-ci chunk -> one 16B store. Blocks 0..127 also
// build one wfrag element/thread; blocks 128..143 zero the accumulator.
// wfrag[p][q][lane][j]: p=ph*2+pw, q=tap*4+ci_blk, lane&31=co,
// ci=(q&3)*16+(lane>>5)*8+j, tap tq=(a,b): kh=2a+1-ph, kw=2b+1-pw.
__global__ __launch_bounds__(256) void prep_transpose(
    const float* __restrict__ x, short* __restrict__ xT,
    const float* __restrict__ w, short* __restrict__ wfrag,
    float* __restrict__ acc)
{
    int b = blockIdx.x, t = threadIdx.x;
    int h = b & 127, n = b >> 7;
    int wv = t >> 6, l = t & 63;

    for (int m = 0; m < 4; ++m) {          // wave-task: oct(8) x w-half(2)
        int task = m * 4 + wv;
        int oct = task >> 1, wt = task & 1;
        int gw = wt * 64 + l;
        short8 o;
        #pragma unroll
        for (int k = 0; k < 8; ++k) {
            float v = x[(((size_t)(n * 64 + oct * 8 + k)) * 128 + h) * 128 + gw];
            o[k] = f2bf(v);
        }
        *(short8*)(xT + (((size_t)(n * 128 + h) * 128 + gw) * 64 + oct * 8)) = o;
    }

    if (b < 128) {                          // weight A-fragments (one elem/thread)
        int idx = b * 256 + t;              // 0..32767
        int j    = idx & 7;
        int lane = (idx >> 3) & 63;
        int q    = (idx >> 9) & 15;
        int p    = idx >> 13;
        int co = lane & 31, half = lane >> 5;
        int ci = (q & 3) * 16 + half * 8 + j;
        int tq = q >> 2, a = tq >> 1, bb = tq & 1;
        int ph = p >> 1, pw = p & 1;
        int kh = 2 * a + 1 - ph, kw = 2 * bb + 1 - pw;
        wfrag[idx] = f2bf(w[((ci * 32 + co) * 4 + kh) * 4 + kw]);
    } else if (b < 144) {
        acc[(b - 128) * 256 + t] = 0.f;
    }
}

// convt_direct: block = (n, row-pair i0, col-half jh); 4 waves = 4 output
// parities. B-fragments come straight from global xT (one 16B dwordx4 per
// lane per MFMA, L1/L2 reuse across taps/parities); OOB lanes clamped and
// cndmask-zeroed. GEMM co(32) x pixels(32) x K(256) via mfma 32x32x16 bf16,
// min over co, fold parities+row-pair -> one atomicAdd per (n,ow).
__global__ __launch_bounds__(256, 4) void convt_direct(
    const short* __restrict__ xT, const short* __restrict__ wfrag,
    const float* __restrict__ conv_b, float* __restrict__ acc4096)
{
    __shared__ float minbuf[2][4][64];

    int blk = blockIdx.x;
    int jh = blk & 1;
    int i0 = ((blk >> 1) & 63) * 2;
    int n  = blk >> 7;
    int t  = threadIdx.x;
    int wv = t >> 6, lane = t & 63;        // wave = parity (ph,pw)
    int ph = wv >> 1, pw = wv & 1;
    int ln = lane & 31, half = lane >> 5;

    // A fragments resident in VGPRs (16 x 16B loads from wfrag, MFMA layout)
    short8 af[16];
    const short8* wf = (const short8*)(wfrag + wv * 8192);
    #pragma unroll
    for (int q = 0; q < 16; ++q) af[q] = wf[q * 64 + lane];

    // conv_b seed in C/D layout: row(co) = (reg&3) + 8*(reg>>2) + 4*half (m74/m101)
    float cb[16];
    #pragma unroll
    for (int reg = 0; reg < 16; ++reg)
        cb[reg] = conv_b[(reg & 3) + 8 * (reg >> 2) + 4 * half];

    const short8 ZERO8 = {0, 0, 0, 0, 0, 0, 0, 0};
    const short* xn = xT + (size_t)n * 128 * 128 * 64;

    #pragma unroll
    for (int rp = 0; rp < 2; ++rp) {
        int gi0 = i0 + rp + ph;            // tap a=0 input row (wave-uniform)
        int gi1 = gi0 - 1;                 // tap a=1
        bool rok0 = (unsigned)gi0 < 128u;
        bool rok1 = (unsigned)gi1 < 128u;
        const short* row0 = xn + (size_t)min(max(gi0, 0), 127) * (128 * 64);
        const short* row1 = xn + (size_t)min(max(gi1, 0), 127) * (128 * 64);

        for (int j0 = 0; j0 < 64; j0 += 32) {
            int gwq0 = jh * 64 + j0 + ln + pw;   // tap b=0 input col (per-lane)
            int gwq1 = gwq0 - 1;                 // tap b=1
            bool cok0 = (unsigned)gwq0 < 128u;
            bool cok1 = (unsigned)gwq1 < 128u;
            int gw0 = min(max(gwq0, 0), 127);
            int gw1 = min(max(gwq1, 0), 127);

            f32x16 acc;
            #pragma unroll
            for (int reg = 0; reg < 16; ++reg) acc[reg] = cb[reg];

            #pragma unroll
            for (int q = 0; q < 16; ++q) {
                int tq = q >> 2;                       // tap = (a,b)
                const short* rbase = (tq & 2) ? row1 : row0;
                bool rok          = (tq & 2) ? rok1 : rok0;
                int gw            = (tq & 1) ? gw1 : gw0;
                bool cok          = (tq & 1) ? cok1 : cok0;
                int ci0 = (q & 3) * 16 + half * 8;
                const short8* bp = (const short8*)(rbase + ((size_t)gw * 64 + ci0));
                short8 bv = *bp;                       // global_load_dwordx4
                if (!(rok && cok)) bv = ZERO8;         // cndmask x4
                acc = __builtin_amdgcn_mfma_f32_32x32x16_bf16(af[q], bv, acc, 0, 0, 0);
            }

            float mn = acc[0];
            #pragma unroll
            for (int reg = 1; reg < 16; ++reg) mn = fminf(mn, acc[reg]);
            mn = fminf(mn, __shfl_xor(mn, 32, 64));    // fold co halves
            if (half == 0) minbuf[rp][wv][j0 + ln] = mn;
        }
    }
    __syncthreads();

    // fold rp + ph -> one atomicAdd per (n,ow), 128/block (r3-proven, no fence)
    if (t < 128) {
        int pw2 = (t >> 6) & 1;
        int jl  = t & 63;
        float v = minbuf[0][pw2][jl] + minbuf[0][2 + pw2][jl]
                + minbuf[1][pw2][jl] + minbuf[1][2 + pw2][jl];
        int ow = ((jh * 64 + jl) << 1) | pw2;
        atomicAdd(&acc4096[n * 256 + ow], v);
    }
}

// GELU(tanh) + bias on the 4096 accumulated sums.
__global__ void finalize(const float* __restrict__ acc4096,
                         const float* __restrict__ bias, float* __restrict__ out)
{
    int idx = blockIdx.x * 256 + threadIdx.x;  // 0..4095
    float s = acc4096[idx];
    float u = 0.7978845608028654f * (s + 0.044715f * s * s * s);
    out[idx] = 0.5f * s * (1.f + tanhf(u)) + bias[0];
}

extern "C" void kernel_launch(void* const* d_in, const int* in_sizes, int n_in,
                              void* d_out, int out_size, void* d_ws, size_t ws_size,
                              hipStream_t stream) {
    const float* x      = (const float*)d_in[0];   // [16,64,128,128]
    const float* w      = (const float*)d_in[1];   // [64,32,4,4]
    const float* conv_b = (const float*)d_in[2];   // [32]
    const float* bias   = (const float*)d_in[3];   // [1]
    float* out = (float*)d_out;                    // 16*256

    float* acc   = (float*)d_ws;                          // 4096 f32   (16 KB)
    short* wfrag = (short*)((char*)d_ws + 16384);         // 32768 bf16 (64 KB)
    short* xT    = (short*)((char*)d_ws + 131072);        // 16*128*128*64 bf16 (32 MB)

    hipLaunchKernelGGL(prep_transpose, dim3(16 * 128), dim3(256), 0, stream,
                       x, xT, w, wfrag, acc);
    hipLaunchKernelGGL(convt_direct, dim3(NITEMS), dim3(256), 0, stream,
                       xT, wfrag, conv_b, acc);
    hipLaunchKernelGGL(finalize, dim3(16), dim3(256), 0, stream,
                       acc, bias, out);
}

// Round 8
// 141.404 us; speedup vs baseline: 2.1128x; 1.2479x over previous
//
#include <hip/hip_runtime.h>
#include <math.h>

typedef __attribute__((ext_vector_type(16))) float f32x16;

#define NITEMS (16 * 64 * 2)

// pack 2 floats -> 2 fp8(e4m3fn on gfx950) bytes; WordSel must be an immediate
template <bool HI>
__device__ __forceinline__ int pk8(float a, float b, int old) {
    return __builtin_amdgcn_cvt_pk_fp8_f32(a, b, old, HI);
}

// prep_transpose: block (n,h) transposes x[n][:,h,:] fp32 -> xT[n][h][w][ci]
// fp8, no LDS: lane l (=w) reads 8 consecutive ci rows coalesced (256B/load)
// and packs pixel l's 8-ci chunk -> one 8B store. Blocks 0..127 also build
// one wfrag byte/thread; blocks 128..143 zero the accumulator.
// wfrag[p][q][lane]: p=ph*2+pw, q=tap*4+ci_blk, lane&31=co,
// ci=(q&3)*16+(lane>>5)*8+j, tap tq: kh=2a+1-ph, kw=2b+1-pw.
__global__ __launch_bounds__(256) void prep_transpose(
    const float* __restrict__ x, unsigned char* __restrict__ xT,
    const float* __restrict__ w, unsigned char* __restrict__ wfrag,
    float* __restrict__ acc)
{
    int b = blockIdx.x, t = threadIdx.x;
    int h = b & 127, n = b >> 7;
    int wv = t >> 6, l = t & 63;

    for (int m = 0; m < 4; ++m) {          // wave-task: oct(8) x w-half(2)
        int task = m * 4 + wv;
        int oct = task >> 1, wt = task & 1;
        int gw = wt * 64 + l;
        float v[8];
        #pragma unroll
        for (int k = 0; k < 8; ++k)
            v[k] = x[(((size_t)(n * 64 + oct * 8 + k)) * 128 + h) * 128 + gw];
        int lo = pk8<false>(v[0], v[1], 0); lo = pk8<true>(v[2], v[3], lo);
        int hi = pk8<false>(v[4], v[5], 0); hi = pk8<true>(v[6], v[7], hi);
        int2 o = make_int2(lo, hi);
        *(int2*)(xT + (((size_t)(n * 128 + h) * 128 + gw) * 64 + oct * 8)) = o;
    }

    if (b < 128) {                          // weight A-fragments (one byte/thread)
        int idx = b * 256 + t;              // 0..32767
        int j    = idx & 7;
        int lane = (idx >> 3) & 63;
        int q    = (idx >> 9) & 15;
        int p    = idx >> 13;
        int co = lane & 31, half = lane >> 5;
        int ci = (q & 3) * 16 + half * 8 + j;
        int tq = q >> 2, a = tq >> 1, bb = tq & 1;
        int ph = p >> 1, pw = p & 1;
        int kh = 2 * a + 1 - ph, kw = 2 * bb + 1 - pw;
        float wval = w[((ci * 32 + co) * 4 + kh) * 4 + kw];
        wfrag[idx] = (unsigned char)(pk8<false>(wval, 0.f, 0) & 0xFF);
    } else if (b < 144) {
        acc[(b - 128) * 256 + t] = 0.f;
    }
}

// convt_direct: block = (n, row-pair i0, col-half jh); 4 waves = 4 output
// parities. B-fragments straight from global xT (8B dwordx2 per lane per
// MFMA, L1/L2 reuse), software-pipelined: tile t+1's 16 loads issue before
// tile t's MFMAs. GEMM co(32) x pixels(32) x K(256) via mfma 32x32x16
// fp8_fp8, min over co, fold parities+row-pair -> one atomicAdd per (n,ow).
__global__ __launch_bounds__(256, 2) void convt_direct(
    const unsigned char* __restrict__ xT, const unsigned char* __restrict__ wfrag,
    const float* __restrict__ conv_b, float* __restrict__ acc4096)
{
    __shared__ float minbuf[2][4][64];

    int blk = blockIdx.x;
    int jh = blk & 1;
    int i0 = ((blk >> 1) & 63) * 2;
    int n  = blk >> 7;
    int t  = threadIdx.x;
    int wv = t >> 6, lane = t & 63;        // wave = parity (ph,pw)
    int ph = wv >> 1, pw = wv & 1;
    int ln = lane & 31, half = lane >> 5;

    // A fragments resident in regs (16 x 8B, MFMA A layout, L2-hot)
    long af[16];
    const long* wf = (const long*)(wfrag) + wv * 1024;   // [p][q][lane]
    #pragma unroll
    for (int q = 0; q < 16; ++q) af[q] = wf[q * 64 + lane];

    // conv_b seed in C/D layout: row(co) = (reg&3) + 8*(reg>>2) + 4*half
    float cb[16];
    #pragma unroll
    for (int reg = 0; reg < 16; ++reg)
        cb[reg] = conv_b[(reg & 3) + 8 * (reg >> 2) + 4 * half];

    const unsigned char* xn = xT + (size_t)n * (128 * 128 * 64);

    // per-tile row/col byte offsets + validity
    int  rowoff[2][2]; bool rokk[2][2];    // [rp][a]
    #pragma unroll
    for (int rp = 0; rp < 2; ++rp) {
        #pragma unroll
        for (int a = 0; a < 2; ++a) {
            int gi = i0 + rp + ph - a;
            rokk[rp][a]   = (unsigned)gi < 128u;
            rowoff[rp][a] = min(max(gi, 0), 127) * 8192;
        }
    }
    int  coloff[2][2]; bool cokk[2][2];    // [jt][b], per-lane
    #pragma unroll
    for (int jt = 0; jt < 2; ++jt) {
        #pragma unroll
        for (int bb = 0; bb < 2; ++bb) {
            int gw = jh * 64 + jt * 32 + ln + pw - bb;
            cokk[jt][bb]   = (unsigned)gw < 128u;
            coloff[jt][bb] = min(max(gw, 0), 127) * 64;
        }
    }

#define LOAD_TILE(dst, RP, JT)                                                 \
    _Pragma("unroll")                                                          \
    for (int q = 0; q < 16; ++q) {                                             \
        int tq = q >> 2;                                                       \
        int ro = rowoff[RP][(tq >> 1) & 1];                                    \
        bool rk = rokk[RP][(tq >> 1) & 1];                                     \
        int co_ = coloff[JT][tq & 1];                                          \
        bool ck = cokk[JT][tq & 1];                                            \
        int ci0 = (q & 3) * 16 + half * 8;                                     \
        long v = *(const long*)(xn + (size_t)(ro + co_ + ci0));                \
        dst[q] = (rk && ck) ? v : 0L;                                          \
    }

    long bv[2][16];
    LOAD_TILE(bv[0], 0, 0);

    #pragma unroll
    for (int tl = 0; tl < 4; ++tl) {       // tile = (rp = tl>>1, jt = tl&1)
        int rp = tl >> 1, jt = tl & 1;
        if (tl == 0) { LOAD_TILE(bv[1], 0, 1); }
        if (tl == 1) { LOAD_TILE(bv[0], 1, 0); }
        if (tl == 2) { LOAD_TILE(bv[1], 1, 1); }

        f32x16 a;
        #pragma unroll
        for (int reg = 0; reg < 16; ++reg) a[reg] = cb[reg];
        #pragma unroll
        for (int q = 0; q < 16; ++q)
            a = __builtin_amdgcn_mfma_f32_32x32x16_fp8_fp8(af[q], bv[tl & 1][q], a, 0, 0, 0);

        float mn = a[0];
        #pragma unroll
        for (int reg = 1; reg < 16; ++reg) mn = fminf(mn, a[reg]);
        mn = fminf(mn, __shfl_xor(mn, 32, 64));     // fold co halves
        if (half == 0) minbuf[rp][wv][jt * 32 + ln] = mn;
    }
#undef LOAD_TILE

    __syncthreads();

    // fold rp + ph -> one atomicAdd per (n,ow), 128/block (r3-proven, no fence)
    if (t < 128) {
        int pw2 = (t >> 6) & 1;
        int jl  = t & 63;
        float v = minbuf[0][pw2][jl] + minbuf[0][2 + pw2][jl]
                + minbuf[1][pw2][jl] + minbuf[1][2 + pw2][jl];
        int ow = ((jh * 64 + jl) << 1) | pw2;
        atomicAdd(&acc4096[n * 256 + ow], v);
    }
}

// GELU(tanh) + bias on the 4096 accumulated sums.
__global__ void finalize(const float* __restrict__ acc4096,
                         const float* __restrict__ bias, float* __restrict__ out)
{
    int idx = blockIdx.x * 256 + threadIdx.x;  // 0..4095
    float s = acc4096[idx];
    float u = 0.7978845608028654f * (s + 0.044715f * s * s * s);
    out[idx] = 0.5f * s * (1.f + tanhf(u)) + bias[0];
}

extern "C" void kernel_launch(void* const* d_in, const int* in_sizes, int n_in,
                              void* d_out, int out_size, void* d_ws, size_t ws_size,
                              hipStream_t stream) {
    const float* x      = (const float*)d_in[0];   // [16,64,128,128]
    const float* w      = (const float*)d_in[1];   // [64,32,4,4]
    const float* conv_b = (const float*)d_in[2];   // [32]
    const float* bias   = (const float*)d_in[3];   // [1]
    float* out = (float*)d_out;                    // 16*256

    float*         acc   = (float*)d_ws;                        // 4096 f32 (16 KB)
    unsigned char* wfrag = (unsigned char*)d_ws + 16384;        // 32 KB
    unsigned char* xT    = (unsigned char*)d_ws + 65536;        // 16 MB fp8

    hipLaunchKernelGGL(prep_transpose, dim3(16 * 128), dim3(256), 0, stream,
                       x, xT, w, wfrag, acc);
    hipLaunchKernelGGL(convt_direct, dim3(NITEMS), dim3(256), 0, stream,
                       xT, wfrag, conv_b, acc);
    hipLaunchKernelGGL(finalize, dim3(16), dim3(256), 0, stream,
                       acc, bias, out);
}